// Round 1
// baseline (24.584 us; speedup 1.0000x reference)
//
#include <hip/hip_runtime.h>

#define Bb 16
#define Tt 64
#define Aa 8
#define Nn 8
#define Ff 16
#define Mm 8
#define FEe 16
#define Ss 10

// Restricted (Myerson-style) value on an 8-node coalition-induced subgraph.
// cm: coalition bitmask; adjrow[k]: adjacency row bitmask (no self loops);
// qv[k]: per-node value. Returns sum over connected components of
// density(comp) * sum(q over comp); singleton density = 1.
__device__ __forceinline__ float restricted_value(unsigned int cm,
                                                  const unsigned int adjrow[8],
                                                  const float qv[8]) {
  unsigned int reach[8];
#pragma unroll
  for (int k = 0; k < 8; ++k) {
    reach[k] = ((cm >> k) & 1u) ? ((adjrow[k] & cm) | (1u << k)) : 0u;
  }
  // Transitive closure: 3 squaring iterations cover diameter <= 8.
#pragma unroll
  for (int it = 0; it < 3; ++it) {
#pragma unroll
    for (int k = 0; k < 8; ++k) {
      unsigned int r = reach[k];
      unsigned int acc = r;
#pragma unroll
      for (int l = 0; l < 8; ++l) {
        if ((r >> l) & 1u) acc |= reach[l];
      }
      reach[k] = acc;
    }
  }
  float total = 0.0f;
#pragma unroll
  for (int l = 0; l < 8; ++l) {
    // l is a component root iff it's in the coalition and the minimum index
    // of its component (no lower bit set in reach[l]).
    if (((cm >> l) & 1u) && ((reach[l] & ((1u << l) - 1u)) == 0u)) {
      unsigned int comp = reach[l];
      int size = __popc(comp);
      float util = 0.0f;
      int edges = 0;  // ordered pairs (k,m) in comp with adj==1
#pragma unroll
      for (int k = 0; k < 8; ++k) {
        if ((comp >> k) & 1u) {
          util += qv[k];
          edges += __popc(adjrow[k] & comp);
        }
      }
      float density = (size > 1) ? ((float)edges / (float)(size * (size - 1)))
                                 : 1.0f;
      total += density * util;
    }
  }
  return total;
}

__global__ __launch_bounds__(128) void GIGM_5952824672776_kernel(
    const float* __restrict__ all_node,   // (B, T+1, A, N, F)
    const float* __restrict__ all_adj,    // (B, T+1, A, N, N)
    const float* __restrict__ ene_node,   // (B, T+1, A, M, FE)
    const float* __restrict__ ene_adj,    // (B, T+1, A, M, M)
    const float* __restrict__ qvals,      // (B, T, A)
    const float* __restrict__ mask,       // (B, T, 1)
    const float* __restrict__ perm_ranks, // (B, T, A, S, N)
    float* __restrict__ out) {            // inc (B,T,A) ++ team (B,T,1)
  const int bt = blockIdx.x;  // 0 .. B*T-1
  const int b = bt / Tt;
  const int t = bt % Tt;
  const int tid = threadIdx.x;

  __shared__ unsigned int s_vis[8];   // visibility bitmask per agent
  __shared__ float s_q[8];
  __shared__ float s_alive[8];
  __shared__ unsigned int s_adj[64];  // [a*8+k] adjacency row bitmasks
  __shared__ float s_diff[80];        // [a*10+s] rv(with)-rv(prev)
  __shared__ float s_emb[2][8][18];   // [which(t/t+1)][a][dim]
  __shared__ float s_alive_e[8];
  __shared__ float s_mu[8];
  __shared__ float s_meanmu;
  __shared__ float s_inc[8];

  // ---------------- Phase A: staging ----------------
  if (tid < 8) {
    const int a = tid;
    const float* nd = all_node + (((b * (Tt + 1) + t) * Aa + a) * Nn * Ff);
    unsigned int v = 0;
#pragma unroll
    for (int n = 0; n < 8; ++n) {
      if (nd[n * Ff] > 0.0f) v |= (1u << n);
    }
    s_vis[a] = v;
    s_alive[a] = (v != 0u) ? 1.0f : 0.0f;
    s_q[a] = qvals[(b * Tt + t) * Aa + a];
  } else if (tid >= 16 && tid < 80) {
    const int idx = tid - 16;
    const int a = idx >> 3;
    const int k = idx & 7;
    const float* ad =
        all_adj + (((b * (Tt + 1) + t) * Aa + a) * Nn * Nn + k * Nn);
    unsigned int r = 0;
#pragma unroll
    for (int l = 0; l < 8; ++l) {
      if (ad[l] > 0.0f) r |= (1u << l);
    }
    s_adj[idx] = r;
  } else if (tid >= 80 && tid < 96) {
    // Enemy embedding for (agent a, time t+which)
    const int idx = tid - 80;
    const int a = idx >> 1;
    const int which = idx & 1;
    const int time = t + which;
    const float* nd = ene_node + (((b * (Tt + 1) + time) * Aa + a) * Mm * FEe);
    const float* ad = ene_adj + (((b * (Tt + 1) + time) * Aa + a) * Mm * Mm);
    float m[8];
    float cnt = 0.0f, mx = -3.0e38f;
#pragma unroll
    for (int j = 0; j < 8; ++j) {
      m[j] = nd[j * FEe];  // feature 0, raw (may be negative)
      cnt += m[j];
      mx = fmaxf(mx, m[j]);
    }
    const float cden = fmaxf(cnt, 1.0f);
#pragma unroll
    for (int f = 0; f < 16; ++f) {
      float sacc = 0.0f;
#pragma unroll
      for (int j = 0; j < 8; ++j) sacc += nd[j * FEe + f] * m[j];
      s_emb[which][a][f] = sacc / cden;
    }
    float deg[8];
    float md = 0.0f;
#pragma unroll
    for (int j = 0; j < 8; ++j) {
      float d = 0.0f;
#pragma unroll
      for (int l = 0; l < 8; ++l) d += ad[j * 8 + l];
      deg[j] = d * (1.0f / 7.0f);  // /(M-1)
      md += deg[j] * m[j];
    }
    md /= cden;
    float vd = 0.0f;
#pragma unroll
    for (int j = 0; j < 8; ++j) {
      const float dd = deg[j] - md;
      vd += dd * dd * m[j];
    }
    vd /= cden;
    s_emb[which][a][16] = md;
    s_emb[which][a][17] = vd;
    if (which == 0) s_alive_e[a] = (mx > 0.0f) ? 1.0f : 0.0f;
  }
  __syncthreads();

  // ---------------- Phase B: coalition marginal values ----------------
  if (tid < 80) {
    const int a = tid / 10;
    const int s = tid % 10;
    const float* pr =
        perm_ranks + ((((b * Tt + t) * Aa + a) * Ss + s) * Nn);
    float rank[8];
#pragma unroll
    for (int n = 0; n < 8; ++n) rank[n] = pr[n];
    const float sr = pr[a];  // direct load: keep indices static elsewhere
    const unsigned int vis = s_vis[a];
    unsigned int prev = 0;
#pragma unroll
    for (int n = 0; n < 8; ++n) {
      if (((vis >> n) & 1u) && (rank[n] < sr)) prev |= (1u << n);
    }
    const unsigned int with_ = prev | (1u << a);
    unsigned int adjrow[8];
#pragma unroll
    for (int k = 0; k < 8; ++k) adjrow[k] = s_adj[a * 8 + k];
    float qv[8];
#pragma unroll
    for (int k = 0; k < 8; ++k) qv[k] = s_q[k];
    const float rv0 = restricted_value(with_, adjrow, qv);
    const float rv1 = restricted_value(prev, adjrow, qv);
    s_diff[tid] = rv0 - rv1;
  }
  __syncthreads();

  // ---------------- Phase C: per-agent mean over samples ----------------
  if (tid < 8) {
    float acc = 0.0f;
#pragma unroll
    for (int s = 0; s < 10; ++s) acc += s_diff[tid * 10 + s];
    const float mc = acc * 0.1f;
    const bool vis_self = ((s_vis[tid] >> tid) & 1u) != 0u;
    s_mu[tid] = vis_self ? mc : 0.0f;
  }
  __syncthreads();
  if (tid == 0) {
    float smu = 0.0f, sal = 0.0f;
#pragma unroll
    for (int a = 0; a < 8; ++a) {
      smu += s_mu[a] * s_alive[a];
      sal += s_alive[a];
    }
    s_meanmu = smu / fmaxf(sal, 1.0f);
  }
  __syncthreads();

  // ---------------- Phase E: intrinsic + extrinsic + write ----------------
  if (tid < 8) {
    const int a = tid;
    float x = s_mu[a] - s_meanmu;
    x = fminf(fmaxf(x, -5.0f), 5.0f);
    const float intrinsic = expf(x) * s_alive[a];

    float pe[18], qe[18];
    float mxp = -3.0e38f, mxq = -3.0e38f;
#pragma unroll
    for (int i = 0; i < 18; ++i) {
      pe[i] = s_emb[1][a][i];
      qe[i] = s_emb[0][a][i];
      mxp = fmaxf(mxp, pe[i]);
      mxq = fmaxf(mxq, qe[i]);
    }
    float sp = 0.0f, sq = 0.0f;
#pragma unroll
    for (int i = 0; i < 18; ++i) {
      pe[i] = expf(pe[i] - mxp);
      sp += pe[i];
      qe[i] = expf(qe[i] - mxq);
      sq += qe[i];
    }
    float kl = 0.0f;
    const float inv_sp = 1.0f / sp;
    const float inv_sq = 1.0f / sq;
#pragma unroll
    for (int i = 0; i < 18; ++i) {
      const float p = pe[i] * inv_sp;
      const float qd = qe[i] * inv_sq;
      kl += p * (logf(p + 1e-8f) - logf(qd + 1e-8f));
    }
    const float extrinsic = kl * s_alive_e[a];
    const float inc =
        (2.0f * intrinsic + 1.0f * extrinsic) * 0.05f * mask[b * Tt + t];
    s_inc[a] = inc;
    out[(b * Tt + t) * Aa + a] = inc;
  }
  __syncthreads();
  if (tid == 0) {
    float team = 0.0f;
#pragma unroll
    for (int a = 0; a < 8; ++a) team += s_inc[a];
    out[Bb * Tt * Aa + bt] = team;  // team section starts at 8192
  }
}

extern "C" void kernel_launch(void* const* d_in, const int* in_sizes, int n_in,
                              void* d_out, int out_size, void* d_ws,
                              size_t ws_size, hipStream_t stream) {
  (void)in_sizes;
  (void)n_in;
  (void)out_size;
  (void)d_ws;
  (void)ws_size;
  const float* all_node = (const float*)d_in[0];
  const float* all_adj = (const float*)d_in[1];
  const float* ene_node = (const float*)d_in[2];
  const float* ene_adj = (const float*)d_in[3];
  const float* qvals = (const float*)d_in[4];
  const float* maskp = (const float*)d_in[5];
  const float* perm_ranks = (const float*)d_in[6];
  float* out = (float*)d_out;

  dim3 grid(Bb * Tt);
  dim3 block(128);
  GIGM_5952824672776_kernel<<<grid, block, 0, stream>>>(
      all_node, all_adj, ene_node, ene_adj, qvals, maskp, perm_ranks, out);
}

// Round 2
// 18.997 us; speedup vs baseline: 1.2941x; 1.2941x over previous
//
#include <hip/hip_runtime.h>

#define Bb 16
#define Tt 64
#define Aa 8
#define Nn 8
#define Ff 16
#define Mm 8
#define FEe 16
#define Ss 10

__device__ __forceinline__ float gsum8(float x) {
  x += __shfl_xor(x, 1);
  x += __shfl_xor(x, 2);
  x += __shfl_xor(x, 4);
  return x;
}
__device__ __forceinline__ float gmax8(float x) {
  x = fmaxf(x, __shfl_xor(x, 1));
  x = fmaxf(x, __shfl_xor(x, 2));
  x = fmaxf(x, __shfl_xor(x, 4));
  return x;
}

// One block per (b,t). Waves 0-1: enemy embeddings (coalesced, shfl-reduced).
// Waves 2-3: staging + coalition marginal values (single closure + merge).
__global__ __launch_bounds__(256) void GIGM_5952824672776_kernel(
    const float* __restrict__ all_node,   // (B, T+1, A, N, F)
    const float* __restrict__ all_adj,    // (B, T+1, A, N, N)
    const float* __restrict__ ene_node,   // (B, T+1, A, M, FE)
    const float* __restrict__ ene_adj,    // (B, T+1, A, M, M)
    const float* __restrict__ qvals,      // (B, T, A)
    const float* __restrict__ maskp,      // (B, T, 1)
    const float* __restrict__ perm_ranks, // (B, T, A, S, N)
    float* __restrict__ out) {            // inc (B,T,A) ++ team (B,T,1)
  const int bt = blockIdx.x;
  const int b = bt >> 6;  // Tt = 64
  const int t = bt & 63;
  const int tid = threadIdx.x;

  __shared__ unsigned int s_vis[8];
  __shared__ float s_q[8];
  __shared__ float s_alive[8];
  __shared__ unsigned int s_adj[64];
  __shared__ float s_diff[80];
  __shared__ float s_emb[2][8][18];
  __shared__ float s_alive_e[8];

  float4 er0{}, er1{}, er2{}, er3{}, ea0{}, ea1{};
  float4 rk0{}, rk1{};
  float sr = 0.0f;

  // ---------------- pre-barrier: issue loads / stage bitmasks ----------------
  if (tid < 128) {
    const int which = tid >> 6;
    const int a = (tid >> 3) & 7;
    const int j = tid & 7;
    const int time = t + which;
    const float* nd =
        ene_node + (size_t)(((b * (Tt + 1) + time) * Aa + a) * Mm + j) * FEe;
    const float* ad =
        ene_adj + (size_t)(((b * (Tt + 1) + time) * Aa + a) * Mm + j) * Mm;
    er0 = *(const float4*)(nd + 0);
    er1 = *(const float4*)(nd + 4);
    er2 = *(const float4*)(nd + 8);
    er3 = *(const float4*)(nd + 12);
    ea0 = *(const float4*)(ad + 0);
    ea1 = *(const float4*)(ad + 4);
  } else {
    if (tid < 208) {  // diff tasks: issue perm_ranks loads early
      const int task = tid - 128;
      const int a = task / 10;
      const int s = task - a * 10;
      const float* pr =
          perm_ranks + (size_t)(((b * Tt + t) * Aa + a) * Ss + s) * Nn;
      rk0 = *(const float4*)(pr + 0);
      rk1 = *(const float4*)(pr + 4);
      sr = pr[a];
    }
    if (tid < 192) {  // 64 threads: adjacency row bitmasks
      const int idx = tid - 128;  // a*8 + k
      const float* ad =
          all_adj + (size_t)((b * (Tt + 1) + t) * Aa) * (Nn * Nn) + idx * 8;
      const float4 c0 = *(const float4*)(ad + 0);
      const float4 c1 = *(const float4*)(ad + 4);
      unsigned int r = 0;
      if (c0.x > 0.0f) r |= 1u;
      if (c0.y > 0.0f) r |= 2u;
      if (c0.z > 0.0f) r |= 4u;
      if (c0.w > 0.0f) r |= 8u;
      if (c1.x > 0.0f) r |= 16u;
      if (c1.y > 0.0f) r |= 32u;
      if (c1.z > 0.0f) r |= 64u;
      if (c1.w > 0.0f) r |= 128u;
      s_adj[idx] = r;
    } else {  // wave 3: visibility via one ballot
      const int lane = tid & 63;  // = a*8 + n
      const int a = lane >> 3;
      const int n = lane & 7;
      const float* nd =
          all_node + (size_t)(((b * (Tt + 1) + t) * Aa + a) * Nn + n) * Ff;
      const float v0 = nd[0];
      const unsigned long long ball = __ballot(v0 > 0.0f);
      if (n == 0) {
        const unsigned int byte = (unsigned int)((ball >> (a * 8)) & 0xFFull);
        s_vis[a] = byte;
        s_alive[a] = (byte != 0u) ? 1.0f : 0.0f;
        s_q[a] = qvals[(b * Tt + t) * Aa + a];
      }
    }
  }
  __syncthreads();

  // ---------------- compute: embed (waves 0-1) || diff (waves 2-3) ----------
  if (tid < 128) {
    const int which = tid >> 6;
    const int a = (tid >> 3) & 7;
    const int j = tid & 7;
    const float row[16] = {er0.x, er0.y, er0.z, er0.w, er1.x, er1.y,
                           er1.z, er1.w, er2.x, er2.y, er2.z, er2.w,
                           er3.x, er3.y, er3.z, er3.w};
    const float mj = row[0];
    const float cnt = gsum8(mj);
    const float cden = fmaxf(cnt, 1.0f);
    float mf[16];
#pragma unroll
    for (int f = 0; f < 16; ++f) mf[f] = gsum8(row[f] * mj) / cden;
    const float deg =
        (ea0.x + ea0.y + ea0.z + ea0.w + ea1.x + ea1.y + ea1.z + ea1.w) *
        (1.0f / 7.0f);  // /(M-1)
    const float md = gsum8(deg * mj) / cden;
    const float dd = deg - md;
    const float vdg = gsum8(dd * dd * mj) / cden;
    const float mx = gmax8(mj);
    if (j == 0) {
#pragma unroll
      for (int f = 0; f < 16; ++f) s_emb[which][a][f] = mf[f];
      s_emb[which][a][16] = md;
      s_emb[which][a][17] = vdg;
      if (which == 0) s_alive_e[a] = (mx > 0.0f) ? 1.0f : 0.0f;
    }
  } else if (tid < 208) {
    const int task = tid - 128;
    const int a = task / 10;
    const float rank[8] = {rk0.x, rk0.y, rk0.z, rk0.w,
                           rk1.x, rk1.y, rk1.z, rk1.w};
    const unsigned int vis = s_vis[a];
    unsigned int prev = 0;
#pragma unroll
    for (int n = 0; n < 8; ++n) {
      if (((vis >> n) & 1u) && (rank[n] < sr)) prev |= (1u << n);
    }
    unsigned int adjr[8];
#pragma unroll
    for (int k = 0; k < 8; ++k) adjr[k] = s_adj[a * 8 + k];
    float qv[8];
#pragma unroll
    for (int k = 0; k < 8; ++k) qv[k] = s_q[k];
    // Connected components of `prev` via in-register transitive closure.
    unsigned int reach[8];
#pragma unroll
    for (int k = 0; k < 8; ++k)
      reach[k] = ((prev >> k) & 1u) ? ((adjr[k] & prev) | (1u << k)) : 0u;
#pragma unroll
    for (int it = 0; it < 3; ++it) {
#pragma unroll
      for (int k = 0; k < 8; ++k) {
        const unsigned int r = reach[k];
        unsigned int acc = r;
#pragma unroll
        for (int l = 0; l < 8; ++l) {
          if ((r >> l) & 1u) acc |= reach[l];
        }
        reach[k] = acc;
      }
    }
    // Merge trick: with = prev ∪ {a}; only components adjacent to `a` change.
    const unsigned int na = adjr[a] & prev;
    unsigned int Drest = 0;
#pragma unroll
    for (int l = 0; l < 8; ++l) {
      if ((na >> l) & 1u) Drest |= reach[l];
    }
    const unsigned int D = Drest | (1u << a);
    float utilD = qv[a];
    int edgesD = __popc(na);  // ordered edges from a into D
#pragma unroll
    for (int k = 0; k < 8; ++k) {
      if ((Drest >> k) & 1u) {
        utilD += qv[k];
        edgesD += __popc(adjr[k] & D);
      }
    }
    const int szD = __popc(D);
    const float vD =
        (szD > 1) ? ((float)edgesD / (float)(szD * (szD - 1))) * utilD : utilD;
    float sub = 0.0f;  // absorbed components' values
#pragma unroll
    for (int l = 0; l < 8; ++l) {
      if (((Drest >> l) & 1u) && ((reach[l] & ((1u << l) - 1u)) == 0u)) {
        const unsigned int comp = reach[l];
        float util = 0.0f;
        int edges = 0;
#pragma unroll
        for (int k = 0; k < 8; ++k) {
          if ((comp >> k) & 1u) {
            util += qv[k];
            edges += __popc(adjr[k] & comp);
          }
        }
        const int sz = __popc(comp);
        sub += (sz > 1) ? ((float)edges / (float)(sz * (sz - 1))) * util : util;
      }
    }
    s_diff[task] = vD - sub;
  }
  __syncthreads();

  // ---------------- finalize: 8 lanes of wave 0 ----------------
  if (tid < 8) {
    const int a = tid;
    float acc = 0.0f;
#pragma unroll
    for (int s = 0; s < 10; ++s) acc += s_diff[a * 10 + s];
    const float mc = acc * 0.1f;
    const bool vis_self = ((s_vis[a] >> a) & 1u) != 0u;
    const float mu = vis_self ? mc : 0.0f;
    const float alive = s_alive[a];
    float smu = mu * alive;
    float sal = alive;
    smu += __shfl_xor(smu, 1);
    smu += __shfl_xor(smu, 2);
    smu += __shfl_xor(smu, 4);
    sal += __shfl_xor(sal, 1);
    sal += __shfl_xor(sal, 2);
    sal += __shfl_xor(sal, 4);
    const float meanmu = smu / fmaxf(sal, 1.0f);
    float x = mu - meanmu;
    x = fminf(fmaxf(x, -5.0f), 5.0f);
    const float intrinsic = expf(x) * alive;

    float pe[18], qe[18];
    float mxp = -3.0e38f, mxq = -3.0e38f;
#pragma unroll
    for (int i = 0; i < 18; ++i) {
      pe[i] = s_emb[1][a][i];
      qe[i] = s_emb[0][a][i];
      mxp = fmaxf(mxp, pe[i]);
      mxq = fmaxf(mxq, qe[i]);
    }
    float sp = 0.0f, sq = 0.0f;
#pragma unroll
    for (int i = 0; i < 18; ++i) {
      pe[i] = expf(pe[i] - mxp);
      sp += pe[i];
      qe[i] = expf(qe[i] - mxq);
      sq += qe[i];
    }
    float kl = 0.0f;
    const float isp = 1.0f / sp;
    const float isq = 1.0f / sq;
#pragma unroll
    for (int i = 0; i < 18; ++i) {
      const float p = pe[i] * isp;
      const float qd = qe[i] * isq;
      kl += p * (logf(p + 1e-8f) - logf(qd + 1e-8f));
    }
    const float extrinsic = kl * s_alive_e[a];
    const float inc = (2.0f * intrinsic + extrinsic) * 0.05f * maskp[bt];
    out[bt * 8 + a] = inc;
    float team = inc;
    team += __shfl_xor(team, 1);
    team += __shfl_xor(team, 2);
    team += __shfl_xor(team, 4);
    if (a == 0) out[Bb * Tt * Aa + bt] = team;
  }
}

extern "C" void kernel_launch(void* const* d_in, const int* in_sizes, int n_in,
                              void* d_out, int out_size, void* d_ws,
                              size_t ws_size, hipStream_t stream) {
  (void)in_sizes;
  (void)n_in;
  (void)out_size;
  (void)d_ws;
  (void)ws_size;
  const float* all_node = (const float*)d_in[0];
  const float* all_adj = (const float*)d_in[1];
  const float* ene_node = (const float*)d_in[2];
  const float* ene_adj = (const float*)d_in[3];
  const float* qvals = (const float*)d_in[4];
  const float* maskp = (const float*)d_in[5];
  const float* perm_ranks = (const float*)d_in[6];
  float* out = (float*)d_out;

  dim3 grid(Bb * Tt);
  dim3 block(256);
  GIGM_5952824672776_kernel<<<grid, block, 0, stream>>>(
      all_node, all_adj, ene_node, ene_adj, qvals, maskp, perm_ranks, out);
}

// Round 4
// 12.167 us; speedup vs baseline: 2.0205x; 1.5613x over previous
//
#include <hip/hip_runtime.h>

#define Bb 16
#define Tt 64
#define Aa 8
#define Nn 8
#define Ff 16
#define Mm 8
#define FEe 16
#define Ss 10

__device__ __forceinline__ float gsum8(float x) {
  x += __shfl_xor(x, 1);
  x += __shfl_xor(x, 2);
  x += __shfl_xor(x, 4);
  return x;
}
__device__ __forceinline__ float gmax8(float x) {
  x = fmaxf(x, __shfl_xor(x, 1));
  x = fmaxf(x, __shfl_xor(x, 2));
  x = fmaxf(x, __shfl_xor(x, 4));
  return x;
}
__device__ __forceinline__ float wsum64(float x) {
  x += __shfl_xor(x, 1);
  x += __shfl_xor(x, 2);
  x += __shfl_xor(x, 4);
  x += __shfl_xor(x, 8);
  x += __shfl_xor(x, 16);
  x += __shfl_xor(x, 32);
  return x;
}

// One block per (b,t), 4 waves, ONE barrier.
// Waves 0-1: enemy embed + in-group softmax + log -> LDS (self-contained).
// Waves 2-3: coalition diffs with WAVE-UNIFORM control flow (wave 3 computes
//            each of its 16 tasks on 4 lanes redundantly so every lane is
//            active when __shfl sources adjacency rows). Wave 0 finalizes.
__global__ __launch_bounds__(256) void GIGM_5952824672776_kernel(
    const float* __restrict__ all_node,   // (B, T+1, A, N, F)
    const float* __restrict__ all_adj,    // (B, T+1, A, N, N)
    const float* __restrict__ ene_node,   // (B, T+1, A, M, FE)
    const float* __restrict__ ene_adj,    // (B, T+1, A, M, M)
    const float* __restrict__ qvals,      // (B, T, A)
    const float* __restrict__ maskp,      // (B, T, 1)
    const float* __restrict__ perm_ranks, // (B, T, A, S, N)
    float* __restrict__ out) {            // inc (B,T,A) ++ team (B,T,1)
  const int bt = blockIdx.x;
  const int b = bt >> 6;  // Tt = 64
  const int t = bt & 63;
  const int tid = threadIdx.x;
  const int wave = tid >> 6;
  const int lane = tid & 63;

  __shared__ float s_diff[80];
  __shared__ unsigned int s_vis[8];
  __shared__ float s_alive_e[8];
  __shared__ float s_p[8][18];   // softmax(emb_tp1)
  __shared__ float s_lp[8][18];  // log(p + eps)
  __shared__ float s_lq[8][18];  // log(q + eps)

  if (wave < 2) {
    // ---------------- enemy embed, which = wave ----------------
    const int which = wave;
    const int a = lane >> 3;
    const int j = lane & 7;
    const int time = t + which;
    const float* nd =
        ene_node + (size_t)(((b * (Tt + 1) + time) * Aa + a) * Mm + j) * FEe;
    const float* ad =
        ene_adj + (size_t)(((b * (Tt + 1) + time) * Aa + a) * Mm + j) * Mm;
    const float4 er0 = *(const float4*)(nd + 0);
    const float4 er1 = *(const float4*)(nd + 4);
    const float4 er2 = *(const float4*)(nd + 8);
    const float4 er3 = *(const float4*)(nd + 12);
    const float4 ea0 = *(const float4*)(ad + 0);
    const float4 ea1 = *(const float4*)(ad + 4);
    const float row[16] = {er0.x, er0.y, er0.z, er0.w, er1.x, er1.y,
                           er1.z, er1.w, er2.x, er2.y, er2.z, er2.w,
                           er3.x, er3.y, er3.z, er3.w};
    const float mj = row[0];
    const float cden = fmaxf(gsum8(mj), 1.0f);
    const float icden = 1.0f / cden;
    float v[18];
#pragma unroll
    for (int f = 0; f < 16; ++f) v[f] = gsum8(row[f] * mj) * icden;
    const float deg =
        (ea0.x + ea0.y + ea0.z + ea0.w + ea1.x + ea1.y + ea1.z + ea1.w) *
        (1.0f / 7.0f);
    const float md = gsum8(deg * mj) * icden;
    v[16] = md;
    const float dd = deg - md;
    v[17] = gsum8(dd * dd * mj) * icden;
    if (which == 0) {
      const float mx_m = gmax8(mj);
      if (j == 0) s_alive_e[a] = (mx_m > 0.0f) ? 1.0f : 0.0f;
    }
    // softmax over 18 dims; every lane of the 8-group holds all 18.
    float mx = v[0];
#pragma unroll
    for (int i = 1; i < 18; ++i) mx = fmaxf(mx, v[i]);
    // lane j owns dims {j, 8+j} and (j<2) dim 16+j.
    float x0 = v[0], x1 = v[8];
#pragma unroll
    for (int d = 1; d < 8; ++d) {
      if (j == d) {
        x0 = v[d];
        x1 = v[8 + d];
      }
    }
    const float x2 = (j == 0) ? v[16] : v[17];
    const float e0 = expf(x0 - mx);
    const float e1 = expf(x1 - mx);
    const float e2 = (j < 2) ? expf(x2 - mx) : 0.0f;
    const float S = gsum8(e0 + e1 + e2);
    const float inv = 1.0f / S;
    const float p0 = e0 * inv, p1 = e1 * inv, p2 = e2 * inv;
    if (which == 1) {
      s_p[a][j] = p0;
      s_p[a][8 + j] = p1;
      s_lp[a][j] = logf(p0 + 1e-8f);
      s_lp[a][8 + j] = logf(p1 + 1e-8f);
      if (j < 2) {
        s_p[a][16 + j] = p2;
        s_lp[a][16 + j] = logf(p2 + 1e-8f);
      }
    } else {
      s_lq[a][j] = logf(p0 + 1e-8f);
      s_lq[a][8 + j] = logf(p1 + 1e-8f);
      if (j < 2) s_lq[a][16 + j] = logf(p2 + 1e-8f);
    }
  } else {
    // ---------------- coalition diffs, wave-uniform flow ------------------
    // Visibility ballot: lane = a*8 + n.
    const float* ndv =
        all_node + ((size_t)((b * (Tt + 1) + t) * Aa) * Nn + lane) * Ff;
    const unsigned long long ball = __ballot(ndv[0] > 0.0f);
    // Adjacency row bitmask: lane = a*8 + k.
    const float* ad =
        all_adj + ((size_t)((b * (Tt + 1) + t) * Aa) * Nn + lane) * Nn;
    const float4 c0 = *(const float4*)(ad + 0);
    const float4 c1 = *(const float4*)(ad + 4);
    unsigned int rowmask = 0;
    if (c0.x > 0.0f) rowmask |= 1u;
    if (c0.y > 0.0f) rowmask |= 2u;
    if (c0.z > 0.0f) rowmask |= 4u;
    if (c0.w > 0.0f) rowmask |= 8u;
    if (c1.x > 0.0f) rowmask |= 16u;
    if (c1.y > 0.0f) rowmask |= 32u;
    if (c1.z > 0.0f) rowmask |= 64u;
    if (c1.w > 0.0f) rowmask |= 128u;
    // Pin: ensure every lane materializes rowmask BEFORE any divergence, so
    // __shfl below never reads a lane that skipped the computation.
    asm volatile("" : "+v"(rowmask));
    if (wave == 3 && (lane & 7) == 0) {
      s_vis[lane >> 3] = (unsigned int)((ball >> lane) & 0xFFull);
    }
    // q broadcast (8 contiguous floats).
    const float* qp = qvals + bt * 8;
    const float4 q0 = *(const float4*)(qp);
    const float4 q1 = *(const float4*)(qp + 4);
    const float qv[8] = {q0.x, q0.y, q0.z, q0.w, q1.x, q1.y, q1.z, q1.w};
    // Task map (ALL lanes active):
    //   wave 2: a = lane>>3, s = lane&7            (64 unique tasks)
    //   wave 3: a = lane>>3, s = 8 + ((lane&7)>>2) (16 tasks x 4 lanes)
    const int a = lane >> 3;
    const int s = (wave == 2) ? (lane & 7) : (8 + ((lane & 7) >> 2));
    const float* pr = perm_ranks + (size_t)((bt * Aa + a) * Ss + s) * Nn;
    const float4 rk0 = *(const float4*)(pr + 0);
    const float4 rk1 = *(const float4*)(pr + 4);
    const float sr = pr[a];
    const float rank[8] = {rk0.x, rk0.y, rk0.z, rk0.w,
                           rk1.x, rk1.y, rk1.z, rk1.w};
    unsigned int adjr[8];
#pragma unroll
    for (int k = 0; k < 8; ++k) adjr[k] = __shfl(rowmask, (a << 3) + k);
    const unsigned int visa = (unsigned int)((ball >> (a << 3)) & 0xFFull);
    unsigned int prev = 0;
#pragma unroll
    for (int n = 0; n < 8; ++n) {
      if (((visa >> n) & 1u) && (rank[n] < sr)) prev |= (1u << n);
    }
    // Connected components of `prev` via in-register transitive closure.
    unsigned int reach[8];
#pragma unroll
    for (int k = 0; k < 8; ++k)
      reach[k] = ((prev >> k) & 1u) ? ((adjr[k] & prev) | (1u << k)) : 0u;
#pragma unroll
    for (int it = 0; it < 3; ++it) {
#pragma unroll
      for (int k = 0; k < 8; ++k) {
        const unsigned int r = reach[k];
        unsigned int acc = r;
#pragma unroll
        for (int l = 0; l < 8; ++l) {
          if ((r >> l) & 1u) acc |= reach[l];
        }
        reach[k] = acc;
      }
    }
    // Merge trick: with = prev ∪ {a}; only comps adjacent to `a` change.
    const unsigned int na = adjr[a] & prev;
    unsigned int Drest = 0;
#pragma unroll
    for (int l = 0; l < 8; ++l) {
      if ((na >> l) & 1u) Drest |= reach[l];
    }
    const unsigned int D = Drest | (1u << a);
    float utilD = qv[a];
    int edgesD = __popc(na);
#pragma unroll
    for (int k = 0; k < 8; ++k) {
      if ((Drest >> k) & 1u) {
        utilD += qv[k];
        edgesD += __popc(adjr[k] & D);
      }
    }
    const int szD = __popc(D);
    const float vD = (szD > 1)
                         ? ((float)edgesD / (float)(szD * (szD - 1))) * utilD
                         : utilD;
    float sub = 0.0f;
#pragma unroll
    for (int l = 0; l < 8; ++l) {
      if (((Drest >> l) & 1u) && ((reach[l] & ((1u << l) - 1u)) == 0u)) {
        const unsigned int comp = reach[l];
        float util = 0.0f;
        int edges = 0;
#pragma unroll
        for (int k = 0; k < 8; ++k) {
          if ((comp >> k) & 1u) {
            util += qv[k];
            edges += __popc(adjr[k] & comp);
          }
        }
        const int sz = __popc(comp);
        sub += (sz > 1) ? ((float)edges / (float)(sz * (sz - 1))) * util : util;
      }
    }
    // wave 2: every lane stores its unique task; wave 3: one of 4 dup lanes.
    if (wave == 2 || (lane & 3) == 0) {
      s_diff[a * 10 + s] = vD - sub;
    }
  }
  __syncthreads();

  // ---------------- finalize: wave 0, 8 lanes per agent ----------------
  if (tid < 64) {
    const int a = tid >> 3;
    const int j = tid & 7;
    float sd = s_diff[a * 10 + j];
    if (j < 2) sd += s_diff[a * 10 + 8 + j];
    const float mc = gsum8(sd) * 0.1f;
    const unsigned int visa = s_vis[a];
    const float alive = (visa != 0u) ? 1.0f : 0.0f;
    const float mu = ((visa >> a) & 1u) ? mc : 0.0f;
    const float c = (j == 0) ? 1.0f : 0.0f;
    const float smu = wsum64(mu * alive * c);
    const float sal = wsum64(alive * c);
    const float meanmu = smu / fmaxf(sal, 1.0f);
    float x = mu - meanmu;
    x = fminf(fmaxf(x, -5.0f), 5.0f);
    const float intr = expf(x) * alive;
    const float p0 = s_p[a][j], p1 = s_p[a][8 + j];
    float klp = p0 * (s_lp[a][j] - s_lq[a][j]) +
                p1 * (s_lp[a][8 + j] - s_lq[a][8 + j]);
    if (j < 2) {
      klp += s_p[a][16 + j] * (s_lp[a][16 + j] - s_lq[a][16 + j]);
    }
    const float kl = gsum8(klp);
    const float inc = (2.0f * intr + kl * s_alive_e[a]) * 0.05f * maskp[bt];
    if (j == 0) out[bt * 8 + a] = inc;
    const float team = wsum64((j == 0) ? inc : 0.0f);
    if (tid == 0) out[Bb * Tt * Aa + bt] = team;
  }
}

extern "C" void kernel_launch(void* const* d_in, const int* in_sizes, int n_in,
                              void* d_out, int out_size, void* d_ws,
                              size_t ws_size, hipStream_t stream) {
  (void)in_sizes;
  (void)n_in;
  (void)out_size;
  (void)d_ws;
  (void)ws_size;
  const float* all_node = (const float*)d_in[0];
  const float* all_adj = (const float*)d_in[1];
  const float* ene_node = (const float*)d_in[2];
  const float* ene_adj = (const float*)d_in[3];
  const float* qvals = (const float*)d_in[4];
  const float* maskp = (const float*)d_in[5];
  const float* perm_ranks = (const float*)d_in[6];
  float* out = (float*)d_out;

  dim3 grid(Bb * Tt);
  dim3 block(256);
  GIGM_5952824672776_kernel<<<grid, block, 0, stream>>>(
      all_node, all_adj, ene_node, ene_adj, qvals, maskp, perm_ranks, out);
}

// Round 6
// 11.647 us; speedup vs baseline: 2.1106x; 1.0446x over previous
//
#include <hip/hip_runtime.h>

#define Bb 16
#define Tt 64
#define Aa 8
#define Nn 8
#define Ff 16
#define Mm 8
#define FEe 16
#define Ss 10

__device__ __forceinline__ float gsum8(float x) {  // reduce within 8-lane group
  x += __shfl_xor(x, 1);
  x += __shfl_xor(x, 2);
  x += __shfl_xor(x, 4);
  return x;
}
__device__ __forceinline__ float asum8(float x) {  // reduce across the 8 groups
  x += __shfl_xor(x, 8);
  x += __shfl_xor(x, 16);
  x += __shfl_xor(x, 32);
  return x;
}

// One block per (b,t), 4 waves, ONE barrier.
// Waves 0-1: enemy embed + softmax + eps-floored logs -> LDS (p, log(p+eps),
//            log(q+eps)).  NOTE: the reference's log(p+1e-8) floor is
//            semantically load-bearing (logits can span ~50 units when
//            count clamps to 1) — do NOT replace with x - logS.
// Waves 2-3: coalition diffs, wave-uniform flow (wave 3: 16 tasks x 4 lanes).
// Wave 0 finalizes (ball_e + mask stay in registers across the barrier).
__global__ __launch_bounds__(256) void GIGM_5952824672776_kernel(
    const float* __restrict__ all_node,   // (B, T+1, A, N, F)
    const float* __restrict__ all_adj,    // (B, T+1, A, N, N)
    const float* __restrict__ ene_node,   // (B, T+1, A, M, FE)
    const float* __restrict__ ene_adj,    // (B, T+1, A, M, M)
    const float* __restrict__ qvals,      // (B, T, A)
    const float* __restrict__ maskp,      // (B, T, 1)
    const float* __restrict__ perm_ranks, // (B, T, A, S, N)
    float* __restrict__ out) {            // inc (B,T,A) ++ team (B,T,1)
  const int bt = blockIdx.x;
  const int b = bt >> 6;  // Tt = 64
  const int t = bt & 63;
  const int tid = threadIdx.x;
  const int wave = tid >> 6;
  const int lane = tid & 63;

  __shared__ float s_diff[80];
  __shared__ unsigned int s_vis[8];
  __shared__ float s_p[8][18];   // softmax(emb_tp1)
  __shared__ float s_lp[8][18];  // log(p + eps)
  __shared__ float s_lq[8][18];  // log(q + eps)

  unsigned long long ball_e = 0;  // wave 0: enemy-alive ballot (survives barrier)
  float maskv = 0.0f;             // wave 0: mask[b,t] prefetch

  if (wave < 2) {
    // ---------------- enemy embed, which = wave ----------------
    const int which = wave;
    const int a = lane >> 3;
    const int j = lane & 7;
    const int time = t + which;
    const float* nd =
        ene_node + (size_t)(((b * (Tt + 1) + time) * Aa + a) * Mm + j) * FEe;
    const float* ad =
        ene_adj + (size_t)(((b * (Tt + 1) + time) * Aa + a) * Mm + j) * Mm;
    const float4 er0 = *(const float4*)(nd + 0);
    const float4 er1 = *(const float4*)(nd + 4);
    const float4 er2 = *(const float4*)(nd + 8);
    const float4 er3 = *(const float4*)(nd + 12);
    const float4 ea0 = *(const float4*)(ad + 0);
    const float4 ea1 = *(const float4*)(ad + 4);
    maskv = maskp[bt];  // uniform scalar prefetch (used post-barrier by wave 0)
    const float row[16] = {er0.x, er0.y, er0.z, er0.w, er1.x, er1.y,
                           er1.z, er1.w, er2.x, er2.y, er2.z, er2.w,
                           er3.x, er3.y, er3.z, er3.w};
    const float mj = row[0];
    ball_e = __ballot(mj > 0.0f);  // whole wave active here
    const float cden = fmaxf(gsum8(mj), 1.0f);
    const float icden = 1.0f / cden;
    float v[18];
#pragma unroll
    for (int f = 0; f < 16; ++f) v[f] = gsum8(row[f] * mj) * icden;
    const float deg =
        (ea0.x + ea0.y + ea0.z + ea0.w + ea1.x + ea1.y + ea1.z + ea1.w) *
        (1.0f / 7.0f);
    const float md = gsum8(deg * mj) * icden;
    v[16] = md;
    const float dd = deg - md;
    v[17] = gsum8(dd * dd * mj) * icden;
    // softmax over 18 dims; every lane of the 8-group holds all 18.
    float mx = v[0];
#pragma unroll
    for (int i = 1; i < 18; ++i) mx = fmaxf(mx, v[i]);
    // lane j owns dims {j, 8+j} and (j<2) dim 16+j (static reg indices).
    float x0 = v[0], x1 = v[8];
#pragma unroll
    for (int d = 1; d < 8; ++d) {
      if (j == d) {
        x0 = v[d];
        x1 = v[8 + d];
      }
    }
    const float x2 = ((j == 0) ? v[16] : v[17]) - mx;
    x0 -= mx;
    x1 -= mx;
    const float e0 = __expf(x0);
    const float e1 = __expf(x1);
    const float e2 = (j < 2) ? __expf(x2) : 0.0f;
    const float S = gsum8(e0 + e1 + e2);
    const float invS = __builtin_amdgcn_rcpf(S);
    const float p0 = e0 * invS;
    const float p1 = e1 * invS;
    const float p2 = e2 * invS;
    if (which == 1) {
      s_p[a][j] = p0;
      s_p[a][8 + j] = p1;
      s_lp[a][j] = __logf(p0 + 1e-8f);
      s_lp[a][8 + j] = __logf(p1 + 1e-8f);
      if (j < 2) {
        s_p[a][16 + j] = p2;
        s_lp[a][16 + j] = __logf(p2 + 1e-8f);
      }
    } else {
      s_lq[a][j] = __logf(p0 + 1e-8f);
      s_lq[a][8 + j] = __logf(p1 + 1e-8f);
      if (j < 2) s_lq[a][16 + j] = __logf(p2 + 1e-8f);
    }
  } else {
    // ---------------- coalition diffs, wave-uniform flow ------------------
    // Visibility ballot: lane = a*8 + n.
    const float* ndv =
        all_node + ((size_t)((b * (Tt + 1) + t) * Aa) * Nn + lane) * Ff;
    const unsigned long long ball = __ballot(ndv[0] > 0.0f);
    // Adjacency row bitmask: lane = a*8 + k.
    const float* ad =
        all_adj + ((size_t)((b * (Tt + 1) + t) * Aa) * Nn + lane) * Nn;
    const float4 c0 = *(const float4*)(ad + 0);
    const float4 c1 = *(const float4*)(ad + 4);
    unsigned int rowmask = 0;
    if (c0.x > 0.0f) rowmask |= 1u;
    if (c0.y > 0.0f) rowmask |= 2u;
    if (c0.z > 0.0f) rowmask |= 4u;
    if (c0.w > 0.0f) rowmask |= 8u;
    if (c1.x > 0.0f) rowmask |= 16u;
    if (c1.y > 0.0f) rowmask |= 32u;
    if (c1.z > 0.0f) rowmask |= 64u;
    if (c1.w > 0.0f) rowmask |= 128u;
    // Pin: every lane materializes rowmask before any divergence (shfl src).
    asm volatile("" : "+v"(rowmask));
    if (wave == 3 && (lane & 7) == 0) {
      s_vis[lane >> 3] = (unsigned int)((ball >> lane) & 0xFFull);
    }
    // q broadcast (8 contiguous floats).
    const float* qp = qvals + bt * 8;
    const float4 q0 = *(const float4*)(qp);
    const float4 q1 = *(const float4*)(qp + 4);
    const float qv[8] = {q0.x, q0.y, q0.z, q0.w, q1.x, q1.y, q1.z, q1.w};
    // Task map (ALL lanes active):
    //   wave 2: a = lane>>3, s = lane&7            (64 unique tasks)
    //   wave 3: a = lane>>3, s = 8 + ((lane&7)>>2) (16 tasks x 4 lanes)
    const int a = lane >> 3;
    const int s = (wave == 2) ? (lane & 7) : (8 + ((lane & 7) >> 2));
    const float* pr = perm_ranks + (size_t)((bt * Aa + a) * Ss + s) * Nn;
    const float4 rk0 = *(const float4*)(pr + 0);
    const float4 rk1 = *(const float4*)(pr + 4);
    const float sr = pr[a];
    const float rank[8] = {rk0.x, rk0.y, rk0.z, rk0.w,
                           rk1.x, rk1.y, rk1.z, rk1.w};
    unsigned int adjr[8];
#pragma unroll
    for (int k = 0; k < 8; ++k) adjr[k] = __shfl(rowmask, (a << 3) + k);
    const unsigned int visa = (unsigned int)((ball >> (a << 3)) & 0xFFull);
    unsigned int prev = 0;
#pragma unroll
    for (int n = 0; n < 8; ++n) {
      if (((visa >> n) & 1u) && (rank[n] < sr)) prev |= (1u << n);
    }
    // Connected components of `prev` via in-register transitive closure.
    unsigned int reach[8];
#pragma unroll
    for (int k = 0; k < 8; ++k)
      reach[k] = ((prev >> k) & 1u) ? ((adjr[k] & prev) | (1u << k)) : 0u;
#pragma unroll
    for (int it = 0; it < 3; ++it) {
#pragma unroll
      for (int k = 0; k < 8; ++k) {
        const unsigned int r = reach[k];
        unsigned int acc = r;
#pragma unroll
        for (int l = 0; l < 8; ++l) {
          if ((r >> l) & 1u) acc |= reach[l];
        }
        reach[k] = acc;
      }
    }
    // Merge trick: with = prev ∪ {a}; only comps adjacent to `a` change.
    const unsigned int na = adjr[a] & prev;
    unsigned int Drest = 0;
#pragma unroll
    for (int l = 0; l < 8; ++l) {
      if ((na >> l) & 1u) Drest |= reach[l];
    }
    const unsigned int D = Drest | (1u << a);
    float utilD = qv[a];
    int edgesD = __popc(na);
#pragma unroll
    for (int k = 0; k < 8; ++k) {
      if ((Drest >> k) & 1u) {
        utilD += qv[k];
        edgesD += __popc(adjr[k] & D);
      }
    }
    const int szD = __popc(D);
    const float vD =
        (szD > 1)
            ? ((float)edgesD *
               __builtin_amdgcn_rcpf((float)(szD * (szD - 1)))) * utilD
            : utilD;
    float sub = 0.0f;
#pragma unroll
    for (int l = 0; l < 8; ++l) {
      if (((Drest >> l) & 1u) && ((reach[l] & ((1u << l) - 1u)) == 0u)) {
        const unsigned int comp = reach[l];
        float util = 0.0f;
        int edges = 0;
#pragma unroll
        for (int k = 0; k < 8; ++k) {
          if ((comp >> k) & 1u) {
            util += qv[k];
            edges += __popc(adjr[k] & comp);
          }
        }
        const int sz = __popc(comp);
        sub += (sz > 1)
                   ? ((float)edges *
                      __builtin_amdgcn_rcpf((float)(sz * (sz - 1)))) * util
                   : util;
      }
    }
    // wave 2: every lane stores its unique task; wave 3: one of 4 dup lanes.
    if (wave == 2 || (lane & 3) == 0) {
      s_diff[a * 10 + s] = vD - sub;
    }
  }
  __syncthreads();

  // ---------------- finalize: wave 0, all 64 lanes ----------------
  if (wave == 0) {
    const int a = lane >> 3;
    const int j = lane & 7;
    float sd = s_diff[a * 10 + j];
    if (j < 2) sd += s_diff[a * 10 + 8 + j];
    const float mc = gsum8(sd) * 0.1f;  // broadcast within group
    const unsigned int visa = s_vis[a];
    const float alive = (visa != 0u) ? 1.0f : 0.0f;
    const float mu = ((visa >> a) & 1u) ? mc : 0.0f;
    // cross-agent sums: value uniform within group -> xor 8/16/32.
    const float smu = asum8(mu * alive);
    const float sal = asum8(alive);
    const float meanmu = smu / fmaxf(sal, 1.0f);
    float x = fminf(fmaxf(mu - meanmu, -5.0f), 5.0f);
    const float intr = __expf(x) * alive;
    // KL with the reference's eps-floored logs.
    const float p0 = s_p[a][j], p1 = s_p[a][8 + j];
    float klp = p0 * (s_lp[a][j] - s_lq[a][j]) +
                p1 * (s_lp[a][8 + j] - s_lq[a][8 + j]);
    if (j < 2) {
      klp += s_p[a][16 + j] * (s_lp[a][16 + j] - s_lq[a][16 + j]);
    }
    const float kl = gsum8(klp);
    const float aliveE = ((ball_e >> (a * 8)) & 0xFFull) ? 1.0f : 0.0f;
    const float inc = (2.0f * intr + kl * aliveE) * 0.05f * maskv;
    if (j == 0) out[bt * 8 + a] = inc;
    const float team = asum8(inc);  // inc uniform within each group
    if (lane == 0) out[Bb * Tt * Aa + bt] = team;
  }
}

extern "C" void kernel_launch(void* const* d_in, const int* in_sizes, int n_in,
                              void* d_out, int out_size, void* d_ws,
                              size_t ws_size, hipStream_t stream) {
  (void)in_sizes;
  (void)n_in;
  (void)out_size;
  (void)d_ws;
  (void)ws_size;
  const float* all_node = (const float*)d_in[0];
  const float* all_adj = (const float*)d_in[1];
  const float* ene_node = (const float*)d_in[2];
  const float* ene_adj = (const float*)d_in[3];
  const float* qvals = (const float*)d_in[4];
  const float* maskp = (const float*)d_in[5];
  const float* perm_ranks = (const float*)d_in[6];
  float* out = (float*)d_out;

  dim3 grid(Bb * Tt);
  dim3 block(256);
  GIGM_5952824672776_kernel<<<grid, block, 0, stream>>>(
      all_node, all_adj, ene_node, ene_adj, qvals, maskp, perm_ranks, out);
}